// Round 3
// baseline (149.878 us; speedup 1.0000x reference)
//
#include <hip/hip_runtime.h>
#include <math.h>

#define D 128
#define KNN 8
#define NSPLIT 16
#define BIGF 3.0e38f
#define C_L2E2 2.0813689810056077f // (log2 e)^2
#define LN2 0.6931471805599453f

typedef __bf16 bf16x8 __attribute__((ext_vector_type(8)));
typedef float f32x4 __attribute__((ext_vector_type(4)));

// -------- fp32 -> swizzled bf16 tiles + sqc = (log2e)^2 * ||x||^2 --------
// Tile = 16 rows. Within tile, 16B chunk at position (ks*64 + q*16 + j) holds
// row j, k-range [(q+4*ks)*8, +8) — i.e. MFMA fragment order, so a fragment
// load is one dwordx4 at base+lane*16.
__global__ void conv_swz_kernel(const float* __restrict__ x, __bf16* __restrict__ xswz,
                                float* __restrict__ sqc, int n) {
    int T = blockIdx.x;
    int lane = threadIdx.x;        // 64
    int j = lane & 15, q = lane >> 4;
    const float* base = x + ((size_t)T * 16 + j) * D + q * 8;
    float s = 0.f;
    #pragma unroll
    for (int ks = 0; ks < 4; ++ks) {
        const float* src = base + ks * 32;
        f32x4 v0 = *(const f32x4*)(src);       // vectorized: 2x dwordx4, was 8 scalar
        f32x4 v1 = *(const f32x4*)(src + 4);
        bf16x8 v;
        #pragma unroll
        for (int e = 0; e < 4; ++e) {
            s += v0[e] * v0[e] + v1[e] * v1[e];
            v[e] = (__bf16)v0[e];
            v[e + 4] = (__bf16)v1[e];
        }
        *(bf16x8*)(xswz + (size_t)T * 2048 + ((size_t)ks * 64 + lane) * 8) = v;
    }
    s += __shfl_xor(s, 16, 64);    // sum over q for fixed j
    s += __shfl_xor(s, 32, 64);
    if (q == 0) sqc[T * 16 + j] = s * C_L2E2;
}

// ---------------- main fused MFMA kernel ----------------
// Block = 4 waves; each wave owns TWO A tiles (32 rows) so every B fragment
// read from L2 feeds two MFMA chains — halves B traffic vs 1-tile/wave
// (1 GB -> 512 MB through TA/L1, the measured invariant wall).
// No LDS, no barriers; B prefetched 1 tile ahead into registers.
// d2' = (log2 e)^2*d2 so exp(-d) = exp2(-sqrt(d2')).
__global__ __launch_bounds__(256, 4)
void knn_mfma(const __bf16* __restrict__ xswz, const float* __restrict__ sqc,
              float* __restrict__ ptop, float* __restrict__ pdn, int n) {
    const int tid  = threadIdx.x;
    const int w    = tid >> 6;               // wave 0..3
    const int lane = tid & 63;
    const int quad = lane >> 4;
    const int l15  = lane & 15;
    const int s    = blockIdx.x >> 4;        // stripe of 128 rows
    const int p    = blockIdx.x & (NSPLIT - 1);
    const int ta0  = s * 8 + w * 2;          // this wave's A tiles
    const int ta1  = ta0 + 1;
    const int tpsplit = (n / 16) / NSPLIT;   // 32 column tiles per block
    const int c0   = p * tpsplit;
    const int NC   = tpsplit;

    // A fragments (swizzled layout: contiguous at lane*16 per ks)
    bf16x8 a0[4], a1[4];
    {
        const __bf16* apt0 = xswz + (size_t)ta0 * 2048 + lane * 8;
        const __bf16* apt1 = xswz + (size_t)ta1 * 2048 + lane * 8;
        #pragma unroll
        for (int ks = 0; ks < 4; ++ks) {
            a0[ks] = *(const bf16x8*)(apt0 + ks * 512);
            a1[ks] = *(const bf16x8*)(apt1 + ks * 512);
        }
    }
    float sqa0[4], sqa1[4];
    #pragma unroll
    for (int r = 0; r < 4; ++r) {
        sqa0[r] = sqc[ta0 * 16 + quad * 4 + r];
        sqa1[r] = sqc[ta1 * 16 + quad * 4 + r];
    }

    float h0a[4], h1a[4], dna[4], h0b[4], h1b[4], dnb[4];
    #pragma unroll
    for (int r = 0; r < 4; ++r) {
        h0a[r] = BIGF; h1a[r] = BIGF; dna[r] = 0.f;
        h0b[r] = BIGF; h1b[r] = BIGF; dnb[r] = 0.f;
    }

    // top-2 update: h1' = med3(h0, h1, v); h0' = min(h0, v)
    // off-diag: d2 is always strongly positive for this data — no clamp needed
    auto epi_fast = [&](const f32x4& acc, float sqb, const float (&sqa)[4],
                        float (&h0)[4], float (&h1)[4], float (&dn)[4]) {
        #pragma unroll
        for (int r = 0; r < 4; ++r) {
            float d2 = fmaf(-2.0f * C_L2E2, acc[r], sqa[r] + sqb);
            float dd = __builtin_amdgcn_sqrtf(d2);
            dn[r] += __builtin_amdgcn_exp2f(-dd);
            float t1 = __builtin_amdgcn_fmed3f(h0[r], h1[r], d2);
            h0[r] = fminf(h0[r], d2);
            h1[r] = t1;
        }
    };
    auto epi_diag = [&](const f32x4& acc, float sqb, bool dt, const float (&sqa)[4],
                        float (&h0)[4], float (&h1)[4], float (&dn)[4]) {
        #pragma unroll
        for (int r = 0; r < 4; ++r) {
            float d2 = fmaxf(fmaf(-2.0f * C_L2E2, acc[r], sqa[r] + sqb), 0.0f);
            bool self = dt && (quad * 4 + r == l15);
            float dd = __builtin_amdgcn_sqrtf(d2);
            float e  = __builtin_amdgcn_exp2f(-dd);
            dn[r] += self ? 0.0f : e;
            float v = self ? BIGF : d2;
            float t1 = __builtin_amdgcn_fmed3f(h0[r], h1[r], v);
            h0[r] = fminf(h0[r], v);
            h1[r] = t1;
        }
    };

    // load one column tile's fragments + its sq term
    auto loadt = [&](bf16x8 (&b)[4], float& sq, int c) {
        const __bf16* bp = xswz + (size_t)c * 2048 + lane * 8;
        #pragma unroll
        for (int ks = 0; ks < 4; ++ks) b[ks] = *(const bf16x8*)(bp + ks * 512);
        sq = sqc[c * 16 + l15];
    };

    auto compute = [&](const bf16x8 (&b)[4], float sqb, int c) {
        f32x4 acc0 = {0.f, 0.f, 0.f, 0.f};
        f32x4 acc1 = {0.f, 0.f, 0.f, 0.f};
        #pragma unroll
        for (int ks = 0; ks < 4; ++ks) {
            acc0 = __builtin_amdgcn_mfma_f32_16x16x32_bf16(a0[ks], b[ks], acc0, 0, 0, 0);
            acc1 = __builtin_amdgcn_mfma_f32_16x16x32_bf16(a1[ks], b[ks], acc1, 0, 0, 0);
        }
        bool dt0 = (c == ta0);
        bool dt1 = (c == ta1);
        if (dt0 || dt1) {                    // wave-uniform, rare
            epi_diag(acc0, sqb, dt0, sqa0, h0a, h1a, dna);
            epi_diag(acc1, sqb, dt1, sqa1, h0b, h1b, dnb);
        } else {
            epi_fast(acc0, sqb, sqa0, h0a, h1a, dna);
            epi_fast(acc1, sqb, sqa1, h0b, h1b, dnb);
        }
    };

    // -------- software-pipelined main loop: prefetch tile c+1 while computing c --------
    // Static double buffer (bA/bB), loop unrolled by 2 so all indexing is compile-time.
    bf16x8 bA[4], bB[4];
    float sA, sB;

    loadt(bA, sA, c0);
    int c = 0;
    for (; c + 2 < NC; c += 2) {
        loadt(bB, sB, c0 + c + 1);
        compute(bA, sA, c0 + c);
        loadt(bA, sA, c0 + c + 2);
        compute(bB, sB, c0 + c + 1);
    }
    loadt(bB, sB, c0 + c + 1);
    compute(bA, sA, c0 + c);
    compute(bB, sB, c0 + c + 1);

    // ---- per-wave merge (wave owns its 32 rows exclusively) ----
    unsigned long long quadmask = 0xFFFFull << (quad * 16);
    auto merge_tile = [&](int ta, float (&h0)[4], float (&h1)[4], float (&dn)[4]) {
        #pragma unroll
        for (int r = 0; r < 4; ++r) {
            float d = dn[r];
            #pragma unroll
            for (int m = 8; m > 0; m >>= 1) d += __shfl_xor(d, m, 64);
            int row = ta * 16 + quad * 4 + r;
            float* pt = ptop + ((size_t)p * n + row) * KNN;
            for (int t = 0; t < KNN; ++t) {
                float lmin = h0[r];
                float gmin = lmin;
                #pragma unroll
                for (int m = 8; m > 0; m >>= 1) gmin = fminf(gmin, __shfl_xor(gmin, m, 64));
                if (l15 == 0) pt[t] = gmin;
                unsigned long long bal = __ballot(lmin == gmin) & quadmask;
                int owner = __ffsll(bal) - 1;
                if (lane == owner) { h0[r] = h1[r]; h1[r] = BIGF; }
            }
            if (l15 == 0) pdn[(size_t)p * n + row] = d;
        }
    };
    merge_tile(ta0, h0a, h1a, dna);
    merge_tile(ta1, h0b, h1b, dnb);
}

// ---------------- final merge: one thread per row ----------------
__global__ void knn_merge(const float* __restrict__ ptop, const float* __restrict__ pdn,
                          float* __restrict__ out, int n) {
    int row = blockIdx.x * blockDim.x + threadIdx.x;
    int lane = threadIdx.x & 63;

    float b8[KNN];
    #pragma unroll
    for (int t = 0; t < KNN; ++t) b8[t] = ptop[(size_t)row * KNN + t];
    float dn = pdn[row];
    for (int sp = 1; sp < NSPLIT; ++sp) {
        dn += pdn[(size_t)sp * n + row];
        const float* pt = ptop + ((size_t)sp * n + row) * KNN;
        #pragma unroll
        for (int t = 0; t < KNN; ++t) {
            float v = pt[t];
            #pragma unroll
            for (int s = 0; s < KNN; ++s) {
                float lo = fminf(b8[s], v);
                v = fmaxf(b8[s], v);
                b8[s] = lo;
            }
        }
    }
    float sumd = 0.0f;
    #pragma unroll
    for (int t = 0; t < KNN; ++t) sumd += sqrtf(b8[t]);   // = d * log2e
    float loss = (sumd * (LN2 / KNN) + logf(dn)) / (float)n;

    #pragma unroll
    for (int m = 32; m > 0; m >>= 1) loss += __shfl_xor(loss, m, 64);
    if (lane == 0) atomicAdd(out, loss);
}

extern "C" void kernel_launch(void* const* d_in, const int* in_sizes, int n_in,
                              void* d_out, int out_size, void* d_ws, size_t ws_size,
                              hipStream_t stream) {
    const float* x = (const float*)d_in[0];
    int n = in_sizes[0] / D;                      // 8192
    char* ws = (char*)d_ws;
    __bf16* xswz = (__bf16*)ws;                   ws += (size_t)n * D * sizeof(__bf16);            // 2 MB
    float*  sqc  = (float*)ws;                    ws += (size_t)n * sizeof(float);                 // 32 KB
    float*  ptop = (float*)ws;                    ws += (size_t)NSPLIT * n * KNN * sizeof(float);  // 4 MB
    float*  pdn  = (float*)ws;                                                                     // 512 KB
    float* out = (float*)d_out;

    hipMemsetAsync(out, 0, sizeof(float), stream);
    conv_swz_kernel<<<n / 16, 64, 0, stream>>>(x, xswz, sqc, n);
    knn_mfma<<<(n / 128) * NSPLIT, 256, 0, stream>>>(xswz, sqc, ptop, pdn, n);
    knn_merge<<<n / 64, 64, 0, stream>>>(ptop, pdn, out, n);
}

// Round 4
// 114.760 us; speedup vs baseline: 1.3060x; 1.3060x over previous
//
#include <hip/hip_runtime.h>
#include <math.h>

#define D 128
#define KNN 8
#define NSPLIT 16
#define BIGF 3.0e38f
#define C_L2E2 2.0813689810056077f // (log2 e)^2
#define LN2 0.6931471805599453f

typedef __bf16 bf16x8 __attribute__((ext_vector_type(8)));
typedef float f32x4 __attribute__((ext_vector_type(4)));

// -------- fp32 -> swizzled bf16 tiles + sqc = (log2e)^2 * ||x||^2 --------
// Tile = 16 rows. Within tile, 16B chunk at position (ks*64 + q*16 + j) holds
// row j, k-range [(q+4*ks)*8, +8) — i.e. MFMA fragment order, so a fragment
// load is one dwordx4 at base+lane*16.
__global__ void conv_swz_kernel(const float* __restrict__ x, __bf16* __restrict__ xswz,
                                float* __restrict__ sqc, int n) {
    int T = blockIdx.x;
    int lane = threadIdx.x;        // 64
    int j = lane & 15, q = lane >> 4;
    const float* base = x + ((size_t)T * 16 + j) * D + q * 8;
    float s = 0.f;
    #pragma unroll
    for (int ks = 0; ks < 4; ++ks) {
        const float* src = base + ks * 32;
        f32x4 v0 = *(const f32x4*)(src);       // vectorized: 2x dwordx4
        f32x4 v1 = *(const f32x4*)(src + 4);
        bf16x8 v;
        #pragma unroll
        for (int e = 0; e < 4; ++e) {
            s += v0[e] * v0[e] + v1[e] * v1[e];
            v[e] = (__bf16)v0[e];
            v[e + 4] = (__bf16)v1[e];
        }
        *(bf16x8*)(xswz + (size_t)T * 2048 + ((size_t)ks * 64 + lane) * 8) = v;
    }
    s += __shfl_xor(s, 16, 64);    // sum over q for fixed j
    s += __shfl_xor(s, 32, 64);
    if (q == 0) sqc[T * 16 + j] = s * C_L2E2;
}

// ---------------- main fused MFMA kernel ----------------
// Block = 4 waves; each wave owns TWO A tiles (32 rows) so every B fragment
// read from L2 feeds two MFMA chains — halves B traffic vs 1-tile/wave.
// No LDS, no barriers; B prefetched 1 tile ahead into registers.
// __launch_bounds__(256,2): VGPR budget 256 — the (256,4) bound capped the
// allocator at 64 VGPR and R3's doubled accumulator state spilled to scratch
// (WRITE_SIZE 4.6->29 MB). ~120 VGPR live is the intended allocation.
// d2' = (log2 e)^2*d2 so exp(-d) = exp2(-sqrt(d2')).
__global__ __launch_bounds__(256, 2)
void knn_mfma(const __bf16* __restrict__ xswz, const float* __restrict__ sqc,
              float* __restrict__ ptop, float* __restrict__ pdn, int n) {
    const int tid  = threadIdx.x;
    const int w    = tid >> 6;               // wave 0..3
    const int lane = tid & 63;
    const int quad = lane >> 4;
    const int l15  = lane & 15;
    const int s    = blockIdx.x >> 4;        // stripe of 128 rows
    const int p    = blockIdx.x & (NSPLIT - 1);
    const int ta0  = s * 8 + w * 2;          // this wave's A tiles
    const int ta1  = ta0 + 1;
    const int tpsplit = (n / 16) / NSPLIT;   // 32 column tiles per block
    const int c0   = p * tpsplit;
    const int NC   = tpsplit;

    // A fragments (swizzled layout: contiguous at lane*16 per ks)
    bf16x8 a0[4], a1[4];
    {
        const __bf16* apt0 = xswz + (size_t)ta0 * 2048 + lane * 8;
        const __bf16* apt1 = xswz + (size_t)ta1 * 2048 + lane * 8;
        #pragma unroll
        for (int ks = 0; ks < 4; ++ks) {
            a0[ks] = *(const bf16x8*)(apt0 + ks * 512);
            a1[ks] = *(const bf16x8*)(apt1 + ks * 512);
        }
    }
    float sqa0[4], sqa1[4];
    #pragma unroll
    for (int r = 0; r < 4; ++r) {
        sqa0[r] = sqc[ta0 * 16 + quad * 4 + r];
        sqa1[r] = sqc[ta1 * 16 + quad * 4 + r];
    }

    float h0a[4], h1a[4], dna[4], h0b[4], h1b[4], dnb[4];
    #pragma unroll
    for (int r = 0; r < 4; ++r) {
        h0a[r] = BIGF; h1a[r] = BIGF; dna[r] = 0.f;
        h0b[r] = BIGF; h1b[r] = BIGF; dnb[r] = 0.f;
    }

    // top-2 update: h1' = med3(h0, h1, v); h0' = min(h0, v)
    // off-diag: d2 is always strongly positive for this data — no clamp needed
    auto epi_fast = [&](const f32x4& acc, float sqb, const float (&sqa)[4],
                        float (&h0)[4], float (&h1)[4], float (&dn)[4]) {
        #pragma unroll
        for (int r = 0; r < 4; ++r) {
            float d2 = fmaf(-2.0f * C_L2E2, acc[r], sqa[r] + sqb);
            float dd = __builtin_amdgcn_sqrtf(d2);
            dn[r] += __builtin_amdgcn_exp2f(-dd);
            float t1 = __builtin_amdgcn_fmed3f(h0[r], h1[r], d2);
            h0[r] = fminf(h0[r], d2);
            h1[r] = t1;
        }
    };
    auto epi_diag = [&](const f32x4& acc, float sqb, bool dt, const float (&sqa)[4],
                        float (&h0)[4], float (&h1)[4], float (&dn)[4]) {
        #pragma unroll
        for (int r = 0; r < 4; ++r) {
            float d2 = fmaxf(fmaf(-2.0f * C_L2E2, acc[r], sqa[r] + sqb), 0.0f);
            bool self = dt && (quad * 4 + r == l15);
            float dd = __builtin_amdgcn_sqrtf(d2);
            float e  = __builtin_amdgcn_exp2f(-dd);
            dn[r] += self ? 0.0f : e;
            float v = self ? BIGF : d2;
            float t1 = __builtin_amdgcn_fmed3f(h0[r], h1[r], v);
            h0[r] = fminf(h0[r], v);
            h1[r] = t1;
        }
    };

    // load one column tile's fragments + its sq term
    auto loadt = [&](bf16x8 (&b)[4], float& sq, int c) {
        const __bf16* bp = xswz + (size_t)c * 2048 + lane * 8;
        #pragma unroll
        for (int ks = 0; ks < 4; ++ks) b[ks] = *(const bf16x8*)(bp + ks * 512);
        sq = sqc[c * 16 + l15];
    };

    auto compute = [&](const bf16x8 (&b)[4], float sqb, int c) {
        f32x4 acc0 = {0.f, 0.f, 0.f, 0.f};
        f32x4 acc1 = {0.f, 0.f, 0.f, 0.f};
        #pragma unroll
        for (int ks = 0; ks < 4; ++ks) {
            acc0 = __builtin_amdgcn_mfma_f32_16x16x32_bf16(a0[ks], b[ks], acc0, 0, 0, 0);
            acc1 = __builtin_amdgcn_mfma_f32_16x16x32_bf16(a1[ks], b[ks], acc1, 0, 0, 0);
        }
        bool dt0 = (c == ta0);
        bool dt1 = (c == ta1);
        if (dt0 || dt1) {                    // wave-uniform, rare
            epi_diag(acc0, sqb, dt0, sqa0, h0a, h1a, dna);
            epi_diag(acc1, sqb, dt1, sqa1, h0b, h1b, dnb);
        } else {
            epi_fast(acc0, sqb, sqa0, h0a, h1a, dna);
            epi_fast(acc1, sqb, sqa1, h0b, h1b, dnb);
        }
    };

    // -------- software-pipelined main loop: prefetch tile c+1 while computing c --------
    // Static double buffer (bA/bB), loop unrolled by 2 so all indexing is compile-time.
    bf16x8 bA[4], bB[4];
    float sA, sB;

    loadt(bA, sA, c0);
    int c = 0;
    for (; c + 2 < NC; c += 2) {
        loadt(bB, sB, c0 + c + 1);
        compute(bA, sA, c0 + c);
        loadt(bA, sA, c0 + c + 2);
        compute(bB, sB, c0 + c + 1);
    }
    loadt(bB, sB, c0 + c + 1);
    compute(bA, sA, c0 + c);
    compute(bB, sB, c0 + c + 1);

    // ---- per-wave merge (wave owns its 32 rows exclusively) ----
    unsigned long long quadmask = 0xFFFFull << (quad * 16);
    auto merge_tile = [&](int ta, float (&h0)[4], float (&h1)[4], float (&dn)[4]) {
        #pragma unroll
        for (int r = 0; r < 4; ++r) {
            float d = dn[r];
            #pragma unroll
            for (int m = 8; m > 0; m >>= 1) d += __shfl_xor(d, m, 64);
            int row = ta * 16 + quad * 4 + r;
            float* pt = ptop + ((size_t)p * n + row) * KNN;
            for (int t = 0; t < KNN; ++t) {
                float lmin = h0[r];
                float gmin = lmin;
                #pragma unroll
                for (int m = 8; m > 0; m >>= 1) gmin = fminf(gmin, __shfl_xor(gmin, m, 64));
                if (l15 == 0) pt[t] = gmin;
                unsigned long long bal = __ballot(lmin == gmin) & quadmask;
                int owner = __ffsll(bal) - 1;
                if (lane == owner) { h0[r] = h1[r]; h1[r] = BIGF; }
            }
            if (l15 == 0) pdn[(size_t)p * n + row] = d;
        }
    };
    merge_tile(ta0, h0a, h1a, dna);
    merge_tile(ta1, h0b, h1b, dnb);
}

// ---------------- final merge: one thread per row ----------------
__global__ void knn_merge(const float* __restrict__ ptop, const float* __restrict__ pdn,
                          float* __restrict__ out, int n) {
    int row = blockIdx.x * blockDim.x + threadIdx.x;
    int lane = threadIdx.x & 63;

    float b8[KNN];
    #pragma unroll
    for (int t = 0; t < KNN; ++t) b8[t] = ptop[(size_t)row * KNN + t];
    float dn = pdn[row];
    for (int sp = 1; sp < NSPLIT; ++sp) {
        dn += pdn[(size_t)sp * n + row];
        const float* pt = ptop + ((size_t)sp * n + row) * KNN;
        #pragma unroll
        for (int t = 0; t < KNN; ++t) {
            float v = pt[t];
            #pragma unroll
            for (int s = 0; s < KNN; ++s) {
                float lo = fminf(b8[s], v);
                v = fmaxf(b8[s], v);
                b8[s] = lo;
            }
        }
    }
    float sumd = 0.0f;
    #pragma unroll
    for (int t = 0; t < KNN; ++t) sumd += sqrtf(b8[t]);   // = d * log2e
    float loss = (sumd * (LN2 / KNN) + logf(dn)) / (float)n;

    #pragma unroll
    for (int m = 32; m > 0; m >>= 1) loss += __shfl_xor(loss, m, 64);
    if (lane == 0) atomicAdd(out, loss);
}

extern "C" void kernel_launch(void* const* d_in, const int* in_sizes, int n_in,
                              void* d_out, int out_size, void* d_ws, size_t ws_size,
                              hipStream_t stream) {
    const float* x = (const float*)d_in[0];
    int n = in_sizes[0] / D;                      // 8192
    char* ws = (char*)d_ws;
    __bf16* xswz = (__bf16*)ws;                   ws += (size_t)n * D * sizeof(__bf16);            // 2 MB
    float*  sqc  = (float*)ws;                    ws += (size_t)n * sizeof(float);                 // 32 KB
    float*  ptop = (float*)ws;                    ws += (size_t)NSPLIT * n * KNN * sizeof(float);  // 4 MB
    float*  pdn  = (float*)ws;                                                                     // 512 KB
    float* out = (float*)d_out;

    hipMemsetAsync(out, 0, sizeof(float), stream);
    conv_swz_kernel<<<n / 16, 64, 0, stream>>>(x, xswz, sqc, n);
    knn_mfma<<<(n / 128) * NSPLIT, 256, 0, stream>>>(xswz, sqc, ptop, pdn, n);
    knn_merge<<<n / 64, 64, 0, stream>>>(ptop, pdn, out, n);
}

// Round 7
// 111.482 us; speedup vs baseline: 1.3444x; 1.0294x over previous
//
#include <hip/hip_runtime.h>
#include <math.h>

#define D 128
#define KNN 8
#define NSPLIT 8
#define BIGF 3.0e38f
#define C_L2E2 2.0813689810056077f // (log2 e)^2
#define LN2 0.6931471805599453f

typedef __bf16 bf16x8 __attribute__((ext_vector_type(8)));
typedef float f32x4 __attribute__((ext_vector_type(4)));

// -------- fp32 -> swizzled bf16 tiles + sqc = (log2e)^2 * ||x||^2 --------
// Tile = 16 rows. Within tile, 16B chunk at position (ks*64 + q*16 + j) holds
// row j, k-range [(q+4*ks)*8, +8) — i.e. MFMA fragment order, so a fragment
// load is one dwordx4 at base+lane*16.
__global__ void conv_swz_kernel(const float* __restrict__ x, __bf16* __restrict__ xswz,
                                float* __restrict__ sqc, int n) {
    int T = blockIdx.x;
    int lane = threadIdx.x;        // 64
    int j = lane & 15, q = lane >> 4;
    const float* base = x + ((size_t)T * 16 + j) * D + q * 8;
    float s = 0.f;
    #pragma unroll
    for (int ks = 0; ks < 4; ++ks) {
        const float* src = base + ks * 32;
        f32x4 v0 = *(const f32x4*)(src);       // vectorized: 2x dwordx4
        f32x4 v1 = *(const f32x4*)(src + 4);
        bf16x8 v;
        #pragma unroll
        for (int e = 0; e < 4; ++e) {
            s += v0[e] * v0[e] + v1[e] * v1[e];
            v[e] = (__bf16)v0[e];
            v[e + 4] = (__bf16)v1[e];
        }
        *(bf16x8*)(xswz + (size_t)T * 2048 + ((size_t)ks * 64 + lane) * 8) = v;
    }
    s += __shfl_xor(s, 16, 64);    // sum over q for fixed j
    s += __shfl_xor(s, 32, 64);
    if (q == 0) sqc[T * 16 + j] = s * C_L2E2;
}

// ---------------- main fused MFMA kernel (R1-proven structure) ----------------
// Block = 4 waves = 64 rows (wave w: rows s*64+16w). NSPLIT=8 column splits.
// No LDS: xswz is 2 MB = fully L2-resident, so B fragments are loaded straight
// from global into registers with a 1-pair-ahead software prefetch. No barriers.
// d2' = (log2 e)^2*d2 so exp(-d) = exp2(-sqrt(d2')).
__global__ __launch_bounds__(256, 4)
void knn_mfma(const __bf16* __restrict__ xswz, const float* __restrict__ sqc,
              float* __restrict__ ptop, float* __restrict__ pdn, int n) {
    const int tid  = threadIdx.x;
    const int w    = tid >> 6;               // wave 0..3
    const int lane = tid & 63;
    const int quad = lane >> 4;
    const int l15  = lane & 15;
    const int s    = blockIdx.x >> 3;        // stripe of 64 rows
    const int p    = blockIdx.x & (NSPLIT - 1);
    const int ta   = s * 4 + w;              // this wave's A tile (16 rows)
    const int tpsplit = (n / 16) / NSPLIT;   // 64 column tiles per block
    const int c0   = p * tpsplit;
    const int NP   = tpsplit / 2;            // 32 tile-pairs

    // A fragments (swizzled layout: contiguous at lane*16 per ks)
    bf16x8 a[4];
    {
        const __bf16* apt = xswz + (size_t)ta * 2048 + lane * 8;
        #pragma unroll
        for (int ks = 0; ks < 4; ++ks) a[ks] = *(const bf16x8*)(apt + ks * 512);
    }
    float sqa[4];
    #pragma unroll
    for (int r = 0; r < 4; ++r) sqa[r] = sqc[ta * 16 + quad * 4 + r];

    float h0[4], h1[4], dn[4];               // per-lane top-2 + denom partials
    #pragma unroll
    for (int r = 0; r < 4; ++r) { h0[r] = BIGF; h1[r] = BIGF; dn[r] = 0.f; }

    // top-2 update: h1' = med3(h0, h1, v); h0' = min(h0, v)
    // off-diag: d2 is always strongly positive for this data — no clamp needed
    auto epi_fast = [&](const f32x4& acc, float sqb) {
        #pragma unroll
        for (int r = 0; r < 4; ++r) {
            float d2 = fmaf(-2.0f * C_L2E2, acc[r], sqa[r] + sqb);
            float dd = __builtin_amdgcn_sqrtf(d2);
            dn[r] += __builtin_amdgcn_exp2f(-dd);
            float t1 = __builtin_amdgcn_fmed3f(h0[r], h1[r], d2);
            h0[r] = fminf(h0[r], d2);
            h1[r] = t1;
        }
    };
    auto epi_diag = [&](const f32x4& acc, float sqb, bool dt) {
        #pragma unroll
        for (int r = 0; r < 4; ++r) {
            float d2 = fmaxf(fmaf(-2.0f * C_L2E2, acc[r], sqa[r] + sqb), 0.0f);
            bool self = dt && (quad * 4 + r == l15);
            float dd = __builtin_amdgcn_sqrtf(d2);
            float e  = __builtin_amdgcn_exp2f(-dd);
            dn[r] += self ? 0.0f : e;
            float v = self ? BIGF : d2;
            float t1 = __builtin_amdgcn_fmed3f(h0[r], h1[r], v);
            h0[r] = fminf(h0[r], v);
            h1[r] = t1;
        }
    };

    // load both tiles of pair pr into register fragments (+ their sq terms)
    auto loadp = [&](bf16x8 (&b1)[4], bf16x8 (&b2)[4], float& sq1, float& sq2, int pr) {
        int c = c0 + pr * 2;
        const __bf16* bp1 = xswz + (size_t)c * 2048 + lane * 8;
        const __bf16* bp2 = bp1 + 2048;
        #pragma unroll
        for (int ks = 0; ks < 4; ++ks) {
            b1[ks] = *(const bf16x8*)(bp1 + ks * 512);
            b2[ks] = *(const bf16x8*)(bp2 + ks * 512);
        }
        sq1 = sqc[c * 16 + l15];
        sq2 = sqc[c * 16 + 16 + l15];
    };

    auto computep = [&](const bf16x8 (&b1)[4], const bf16x8 (&b2)[4],
                        float sq1, float sq2, int pr) {
        f32x4 acc1 = {0.f, 0.f, 0.f, 0.f};
        f32x4 acc2 = {0.f, 0.f, 0.f, 0.f};
        #pragma unroll
        for (int ks = 0; ks < 4; ++ks) {
            acc1 = __builtin_amdgcn_mfma_f32_16x16x32_bf16(a[ks], b1[ks], acc1, 0, 0, 0);
            acc2 = __builtin_amdgcn_mfma_f32_16x16x32_bf16(a[ks], b2[ks], acc2, 0, 0, 0);
        }
        int c1 = c0 + pr * 2;
        int c2 = c1 + 1;
        bool dt1 = (c1 == ta);
        bool dt2 = (c2 == ta);
        if (dt1 || dt2) {                    // wave-uniform, rare
            epi_diag(acc1, sq1, dt1);
            epi_diag(acc2, sq2, dt2);
        } else {
            epi_fast(acc1, sq1);
            epi_fast(acc2, sq2);
        }
    };

    // -------- software-pipelined main loop: prefetch pair pr+1 while computing pr --------
    // Static double buffer (pA/pB), loop unrolled by 2 so all indexing is compile-time.
    bf16x8 pA1[4], pA2[4], pB1[4], pB2[4];
    float sA1, sA2, sB1, sB2;

    loadp(pA1, pA2, sA1, sA2, 0);
    int pr = 0;
    for (; pr + 2 < NP; pr += 2) {
        loadp(pB1, pB2, sB1, sB2, pr + 1);
        computep(pA1, pA2, sA1, sA2, pr);
        loadp(pA1, pA2, sA1, sA2, pr + 2);
        computep(pB1, pB2, sB1, sB2, pr + 1);
    }
    loadp(pB1, pB2, sB1, sB2, pr + 1);
    computep(pA1, pA2, sA1, sA2, pr);
    computep(pB1, pB2, sB1, sB2, pr + 1);

    // ---- per-wave merge (wave owns its 16 rows exclusively) ----
    unsigned long long quadmask = 0xFFFFull << (quad * 16);
    #pragma unroll
    for (int r = 0; r < 4; ++r) {
        float d = dn[r];
        #pragma unroll
        for (int m = 8; m > 0; m >>= 1) d += __shfl_xor(d, m, 64);
        int row = ta * 16 + quad * 4 + r;
        float* pt = ptop + ((size_t)p * n + row) * KNN;
        for (int t = 0; t < KNN; ++t) {
            float lmin = h0[r];
            float gmin = lmin;
            #pragma unroll
            for (int m = 8; m > 0; m >>= 1) gmin = fminf(gmin, __shfl_xor(gmin, m, 64));
            if (l15 == 0) pt[t] = gmin;
            unsigned long long bal = __ballot(lmin == gmin) & quadmask;
            int owner = __ffsll(bal) - 1;
            if (lane == owner) { h0[r] = h1[r]; h1[r] = BIGF; }
        }
        if (l15 == 0) pdn[(size_t)p * n + row] = d;
    }
}

// ---------------- final merge: one WAVE per row ----------------
// Old version: 128 waves chip-wide (0.5/CU), ~600-op serial chain per thread —
// a pure latency kernel, est. 15-25 us of the constant ~55 us tail.
// New: 8192 waves (512 blocks x 16 waves). Lane (sp,t) holds candidate t of
// split sp; top-8 of 64 extracted by 8x {wave-min, sqrt-accumulate ascending
// (same summation order as the old sorted merge), ballot-remove owner}.
__global__ __launch_bounds__(1024)
void knn_merge(const float* __restrict__ ptop, const float* __restrict__ pdn,
               float* __restrict__ out, int n) {
    const int tid  = threadIdx.x;
    const int wv   = tid >> 6;               // wave 0..15
    const int lane = tid & 63;
    const int row  = blockIdx.x * 16 + wv;
    const int sp   = lane >> 3;              // split 0..7
    const int t    = lane & 7;               // candidate 0..7

    float val = ptop[((size_t)sp * n + row) * KNN + t];
    float dnv = (t == 0) ? pdn[(size_t)sp * n + row] : 0.f;
    #pragma unroll
    for (int m = 32; m > 0; m >>= 1) dnv += __shfl_xor(dnv, m, 64);

    float sumd = 0.f;
    #pragma unroll
    for (int k = 0; k < KNN; ++k) {
        float gmin = val;
        #pragma unroll
        for (int m = 32; m > 0; m >>= 1) gmin = fminf(gmin, __shfl_xor(gmin, m, 64));
        sumd += sqrtf(gmin);                 // ascending order, = d * log2e
        unsigned long long bal = __ballot(val == gmin);
        int owner = __ffsll(bal) - 1;
        if (lane == owner) val = BIGF;
    }
    float loss = (sumd * (LN2 / KNN) + logf(dnv)) / (float)n;

    __shared__ float red[16];
    if (lane == 0) red[wv] = loss;
    __syncthreads();
    if (tid == 0) {
        float v = 0.f;
        #pragma unroll
        for (int i = 0; i < 16; ++i) v += red[i];
        atomicAdd(out, v);                   // 512 atomics total
    }
}

extern "C" void kernel_launch(void* const* d_in, const int* in_sizes, int n_in,
                              void* d_out, int out_size, void* d_ws, size_t ws_size,
                              hipStream_t stream) {
    const float* x = (const float*)d_in[0];
    int n = in_sizes[0] / D;                      // 8192
    char* ws = (char*)d_ws;
    __bf16* xswz = (__bf16*)ws;                   ws += (size_t)n * D * sizeof(__bf16);            // 2 MB
    float*  sqc  = (float*)ws;                    ws += (size_t)n * sizeof(float);                 // 32 KB
    float*  ptop = (float*)ws;                    ws += (size_t)NSPLIT * n * KNN * sizeof(float);  // 2 MB
    float*  pdn  = (float*)ws;                                                                     // 256 KB
    float* out = (float*)d_out;

    hipMemsetAsync(out, 0, sizeof(float), stream);
    conv_swz_kernel<<<n / 16, 64, 0, stream>>>(x, xswz, sqc, n);
    knn_mfma<<<(n / 64) * NSPLIT, 256, 0, stream>>>(xswz, sqc, ptop, pdn, n);
    knn_merge<<<n / 16, 1024, 0, stream>>>(ptop, pdn, out, n);
}